// Round 17
// baseline (423.172 us; speedup 1.0000x reference)
//
#include <hip/hip_runtime.h>
#include <stdint.h>

typedef __bf16 bf16;
typedef __attribute__((ext_vector_type(8))) bf16 bf16x8;
typedef __attribute__((ext_vector_type(4))) bf16 bf16x4;
typedef __attribute__((ext_vector_type(4))) float f32x4;

#define T_DIM 512
#define H_DIM 4096
#define F_DIM 14336

// Tile = 128 rows x 64 cols bf16 = 16 KB, XOR-swizzled: elem = r*64 + (c ^ ((r&7)<<3)).
__device__ __forceinline__ int swz(int r, int c) {
    return r * 64 + (c ^ ((r & 7) << 3));
}

__device__ __forceinline__ int xcd_remap(int d, int chunk) {
    return (d & 7) * chunk + (d >> 3);
}

// async global->LDS, 16B/lane. SOURCE is per-lane; DEST is wave-uniform base
// (HW adds lane*16 to the DEST only) — m104 rule, r16's bug was uniform src.
__device__ __forceinline__ void dma16(const void* g, void* l) {
    __builtin_amdgcn_global_load_lds(
        (const __attribute__((address_space(1))) void*)g,
        (__attribute__((address_space(3))) void*)l, 16, 0, 0);
}

// Race-safe nodrain barrier (validated r7/r9/r13/r14/r15).
__device__ __forceinline__ void barrier_nodrain() {
    __builtin_amdgcn_sched_barrier(0);
    asm volatile("s_waitcnt lgkmcnt(0)\n\ts_barrier" ::: "memory");
    __builtin_amdgcn_sched_barrier(0);
}

// Counted-vmcnt fused barrier (validated r10): waits until only the N newest
// vmem ops are outstanding (forces older DMA complete; prefetch stays live).
#define BARRIER_VM(N)                                                        \
    {                                                                        \
        __builtin_amdgcn_sched_barrier(0);                                   \
        asm volatile("s_waitcnt vmcnt(" #N ") lgkmcnt(0)\n\ts_barrier" ::: "memory"); \
        __builtin_amdgcn_sched_barrier(0);                                   \
    }

// ---------------------------------------------------------------------------
// x (f32 [512][4096]) -> xb tiled: [panel p=m>>7][ktile c>>6][swz(r,c) tile]
__global__ void cvt_x_kernel(const float* __restrict__ x, bf16* __restrict__ xbt) {
    int i = (blockIdx.x * 256 + threadIdx.x) * 4;
    int m = i >> 12;
    int c = i & 4095;
    float4 v = *(const float4*)(x + i);
    bf16x4 o = {(bf16)v.x, (bf16)v.y, (bf16)v.z, (bf16)v.w};
    int p = m >> 7, rm = m & 127, kt = c >> 6, kc = c & 63;
    *(bf16x4*)(xbt + (size_t)(p * 64 + kt) * 8192 + swz(rm, kc)) = o;
}

// ---------------------------------------------------------------------------
// Fused gate+up, phase-split schedule:
// 512 thr (8 waves 2Mx4N), tile 128(M)x128(N), BK=64, wave-tile 64x32 (both W).
// Per K-tile: P1{DMA A(t+1); dsread kk0; bar; prio MFMA16} P2{dsread kk1; bar;
// prio MFMA16} P3{dequant W(t+1)->Bs[nxt]; refill q/sz(t+2); vmcnt(12)-bar}.
__global__ __launch_bounds__(512, 2)
void gemm_gateup(const bf16* __restrict__ A,   // tiled xb
                 const int* __restrict__ Wq1, const float* __restrict__ Sc1,
                 const float* __restrict__ Zr1,
                 const int* __restrict__ Wq3, const float* __restrict__ Sc3,
                 const float* __restrict__ Zr3,
                 bf16* __restrict__ inter) {   // tiled output
    constexpr int KD = H_DIM;
    constexpr int NT = KD / 64;                     // 64
    __shared__ __align__(16) bf16 As[2][128 * 64];  // 32 KB
    __shared__ __align__(16) bf16 Bs1[2][128 * 64]; // 32 KB
    __shared__ __align__(16) bf16 Bs3[2][128 * 64]; // 32 KB

    const int l    = xcd_remap(blockIdx.x, 56);     // 448/8
    const int bx   = l & 3;                         // M panel (replicas co-XCD)
    const int by   = l >> 2;                        // N block 0..111
    const int tid  = threadIdx.x;
    const int lane = tid & 63;
    const int wid  = tid >> 6;                      // 0..7
    const int wm   = wid >> 2;                      // 0..1
    const int wn   = wid & 3;                       // 0..3
    const int lr   = lane & 15;
    const int lk   = (lane >> 4) * 8;
    const int n0   = by * 128;

    const int b_r = (tid >> 4) * 4;
    const int b_c = (tid & 15) * 4;
    const int grp = by * 2 + (b_r >> 6);

    const char* atile  = (const char*)A + (size_t)bx * 64 * 16384;
    const int dma_src = wid * 1024 + lane * 16;     // per-lane GLOBAL source
    const int dma_dst = wid * 1024;                 // wave-uniform LDS base

    const int*   q1B = Wq1 + (size_t)(n0 + b_r) * KD + b_c;
    const int*   q3B = Wq3 + (size_t)(n0 + b_r) * KD + b_c;
    const float* s1B = Sc1 + (size_t)grp * KD + b_c;
    const float* z1B = Zr1 + (size_t)grp * KD + b_c;
    const float* s3B = Sc3 + (size_t)grp * KD + b_c;
    const float* z3B = Zr3 + (size_t)grp * KD + b_c;

    f32x4 acc1[4][2], acc3[4][2];
    const f32x4 zf = {0.f, 0.f, 0.f, 0.f};
#pragma unroll
    for (int i = 0; i < 4; i++)
#pragma unroll
        for (int j = 0; j < 2; j++) { acc1[i][j] = zf; acc3[i][j] = zf; }

    int4   q1r[4], q3r[4];            // 1-deep, refill-after-consume
    float4 s1r, z1r, s3r, z3r;

#define GU_DMA(TILE, nb)                                                      \
    {                                                                         \
        const char* _s = atile + (size_t)(TILE) * 16384 + dma_src;            \
        char* _d = (char*)&As[nb][0] + dma_dst;                               \
        dma16(_s, _d);                                                        \
        dma16(_s + 8192, _d + 8192);                                          \
    }

#define GU_QSZ(K0)                                                            \
    {                                                                         \
        _Pragma("unroll")                                                     \
        for (int i = 0; i < 4; i++) {                                         \
            q1r[i] = *(const int4*)(q1B + (size_t)i * KD + (K0));             \
            q3r[i] = *(const int4*)(q3B + (size_t)i * KD + (K0));             \
        }                                                                     \
        s1r = *(const float4*)(s1B + (K0));                                   \
        z1r = *(const float4*)(z1B + (K0));                                   \
        s3r = *(const float4*)(s3B + (K0));                                   \
        z3r = *(const float4*)(z3B + (K0));                                   \
    }

#define GU_WB(nb)                                                             \
    {                                                                         \
        float4 n1, n3;                                                        \
        n1.x = -z1r.x * s1r.x; n1.y = -z1r.y * s1r.y;                         \
        n1.z = -z1r.z * s1r.z; n1.w = -z1r.w * s1r.w;                         \
        n3.x = -z3r.x * s3r.x; n3.y = -z3r.y * s3r.y;                         \
        n3.z = -z3r.z * s3r.z; n3.w = -z3r.w * s3r.w;                         \
        _Pragma("unroll")                                                     \
        for (int i = 0; i < 4; i++) {                                         \
            bf16x4 v;                                                         \
            v[0] = (bf16)fmaf((float)q1r[i].x, s1r.x, n1.x);                  \
            v[1] = (bf16)fmaf((float)q1r[i].y, s1r.y, n1.y);                  \
            v[2] = (bf16)fmaf((float)q1r[i].z, s1r.z, n1.z);                  \
            v[3] = (bf16)fmaf((float)q1r[i].w, s1r.w, n1.w);                  \
            *(bf16x4*)&Bs1[nb][swz(b_r + i, b_c)] = v;                        \
            bf16x4 u;                                                         \
            u[0] = (bf16)fmaf((float)q3r[i].x, s3r.x, n3.x);                  \
            u[1] = (bf16)fmaf((float)q3r[i].y, s3r.y, n3.y);                  \
            u[2] = (bf16)fmaf((float)q3r[i].z, s3r.z, n3.z);                  \
            u[3] = (bf16)fmaf((float)q3r[i].w, s3r.w, n3.w);                  \
            *(bf16x4*)&Bs3[nb][swz(b_r + i, b_c)] = u;                        \
        }                                                                     \
    }

#define GU_MFMA_K(nb, kk)                                                     \
    {                                                                         \
        bf16x8 af[4], b1[2], b3[2];                                           \
        _Pragma("unroll")                                                     \
        for (int mi = 0; mi < 4; mi++)                                        \
            af[mi] = *(const bf16x8*)&As[nb][swz(wm * 64 + mi * 16 + lr, (kk) * 32 + lk)]; \
        _Pragma("unroll")                                                     \
        for (int ni = 0; ni < 2; ni++) {                                      \
            b1[ni] = *(const bf16x8*)&Bs1[nb][swz(wn * 32 + ni * 16 + lr, (kk) * 32 + lk)]; \
            b3[ni] = *(const bf16x8*)&Bs3[nb][swz(wn * 32 + ni * 16 + lr, (kk) * 32 + lk)]; \
        }                                                                     \
        barrier_nodrain();                                                    \
        __builtin_amdgcn_s_setprio(1);                                        \
        _Pragma("unroll")                                                     \
        for (int mi = 0; mi < 4; mi++)                                        \
            _Pragma("unroll")                                                 \
            for (int ni = 0; ni < 2; ni++) {                                  \
                acc1[mi][ni] = __builtin_amdgcn_mfma_f32_16x16x32_bf16(af[mi], b1[ni], acc1[mi][ni], 0, 0, 0); \
                acc3[mi][ni] = __builtin_amdgcn_mfma_f32_16x16x32_bf16(af[mi], b3[ni], acc3[mi][ni], 0, 0, 0); \
            }                                                                 \
        __builtin_amdgcn_s_setprio(0);                                        \
    }

    // Prologue: W(0)->Bs[0]; DMA A(0)->As[0]; q/sz(1) in flight.
    GU_QSZ(0);
    GU_DMA(0, 0);
    GU_WB(0);                  // compiler waits q(0)/sz(0) only
    GU_QSZ(64);
    BARRIER_VM(12);            // 12 newest = q(1)+sz(1) -> DMA(0) complete

    for (int t = 0; t < NT; ++t) {
        const int cur = t & 1;
        // P1: issue next A DMA early; frags kk0; bar; MFMA
        if (t + 1 < NT) GU_DMA(t + 1, cur ^ 1);
        GU_MFMA_K(cur, 0);
        // P2: frags kk1; bar; MFMA
        GU_MFMA_K(cur, 1);
        // P3: dequant W(t+1) -> Bs[nxt]; refill q/sz(t+2); counted barrier
        if (t + 1 < NT) {
            GU_WB(cur ^ 1);                       // consumes q/sz(t+1)
            if (t + 2 < NT) {
                GU_QSZ((t + 2) * 64);
                BARRIER_VM(12);                   // DMA(t+1) forced complete
            } else {
                BARRIER_VM(0);
            }
        }
    }
#undef GU_DMA
#undef GU_QSZ
#undef GU_WB
#undef GU_MFMA_K

    // Epilogue: silu(gate)*up -> tiled inter.
    const int orow = (lane >> 4) * 4;
#pragma unroll
    for (int mi = 0; mi < 4; mi++)
#pragma unroll
        for (int ni = 0; ni < 2; ni++) {
            int cg = n0 + wn * 32 + ni * 16 + lr;
            int kt = cg >> 6, kc = cg & 63;
            bf16* itile = inter + (size_t)(bx * 224 + kt) * 8192;
#pragma unroll
            for (int r = 0; r < 4; r++) {
                int rm = wm * 64 + mi * 16 + orow + r;
                float g = acc1[mi][ni][r];
                float u = acc3[mi][ni][r];
                float s = g / (1.0f + __expf(-g));
                itile[swz(rm, kc)] = (bf16)(s * u);
            }
        }
}

// ---------------------------------------------------------------------------
// Down proj, split-K, same phase-split schedule, single weight.
// 512 thr, tile 128x128, A DMA'd from tiled inter. grid 4*32*SPLITK.
template<int SPLITK>
__global__ __launch_bounds__(512, 2)
void gemm_down(const bf16* __restrict__ A,    // tiled inter
               const int* __restrict__ Wq,
               const float* __restrict__ Sc, const float* __restrict__ Zr,
               float* __restrict__ partials) {
    constexpr int KD = F_DIM;
    constexpr int KC = KD / SPLITK;
    constexpr int NT = KC / 64;                     // 56
    __shared__ __align__(16) bf16 As[2][128 * 64];  // 32 KB
    __shared__ __align__(16) bf16 Bs[2][128 * 64];  // 32 KB

    const int l    = xcd_remap(blockIdx.x, 16 * SPLITK);
    const int bx   = l & 3;
    const int by   = (l >> 2) & 31;
    const int bz   = l >> 7;
    const int tid  = threadIdx.x;
    const int lane = tid & 63;
    const int wid  = tid >> 6;
    const int wm   = wid >> 2, wn = wid & 3;
    const int lr   = lane & 15;
    const int lk   = (lane >> 4) * 8;
    const int m0   = bx * 128;
    const int n0   = by * 128;
    const int kbeg = bz * KC;
    const int kt0  = bz * NT;

    const int b_r = (tid >> 4) * 4;
    const int b_c = (tid & 15) * 4;
    const int grp = by * 2 + (b_r >> 6);

    const char* atile  = (const char*)A + (size_t)(bx * 224 + kt0) * 16384;
    const int dma_src = wid * 1024 + lane * 16;     // per-lane GLOBAL source
    const int dma_dst = wid * 1024;                 // wave-uniform LDS base

    const int*   qB  = Wq + (size_t)(n0 + b_r) * KD + kbeg + b_c;
    const float* sB_ = Sc + (size_t)grp * KD + kbeg + b_c;
    const float* zB_ = Zr + (size_t)grp * KD + kbeg + b_c;

    f32x4 acc[4][2];
    const f32x4 zf = {0.f, 0.f, 0.f, 0.f};
#pragma unroll
    for (int i = 0; i < 4; i++)
#pragma unroll
        for (int j = 0; j < 2; j++) acc[i][j] = zf;

    int4   qr[4];
    float4 sr, zr;

#define GD_DMA(TILE, nb)                                                      \
    {                                                                         \
        const char* _s = atile + (size_t)(TILE) * 16384 + dma_src;            \
        char* _d = (char*)&As[nb][0] + dma_dst;                               \
        dma16(_s, _d);                                                        \
        dma16(_s + 8192, _d + 8192);                                          \
    }

#define GD_QSZ(K0)                                                            \
    {                                                                         \
        _Pragma("unroll")                                                     \
        for (int i = 0; i < 4; i++)                                           \
            qr[i] = *(const int4*)(qB + (size_t)i * KD + (K0));               \
        sr = *(const float4*)(sB_ + (K0));                                    \
        zr = *(const float4*)(zB_ + (K0));                                    \
    }

#define GD_WB(nb)                                                             \
    {                                                                         \
        float4 nz;                                                            \
        nz.x = -zr.x * sr.x; nz.y = -zr.y * sr.y;                             \
        nz.z = -zr.z * sr.z; nz.w = -zr.w * sr.w;                             \
        _Pragma("unroll")                                                     \
        for (int i = 0; i < 4; i++) {                                         \
            bf16x4 v;                                                         \
            v[0] = (bf16)fmaf((float)qr[i].x, sr.x, nz.x);                    \
            v[1] = (bf16)fmaf((float)qr[i].y, sr.y, nz.y);                    \
            v[2] = (bf16)fmaf((float)qr[i].z, sr.z, nz.z);                    \
            v[3] = (bf16)fmaf((float)qr[i].w, sr.w, nz.w);                    \
            *(bf16x4*)&Bs[nb][swz(b_r + i, b_c)] = v;                         \
        }                                                                     \
    }

#define GD_MFMA_K(nb, kk)                                                     \
    {                                                                         \
        bf16x8 af[4], bv[2];                                                  \
        _Pragma("unroll")                                                     \
        for (int mi = 0; mi < 4; mi++)                                        \
            af[mi] = *(const bf16x8*)&As[nb][swz(wm * 64 + mi * 16 + lr, (kk) * 32 + lk)]; \
        _Pragma("unroll")                                                     \
        for (int ni = 0; ni < 2; ni++)                                        \
            bv[ni] = *(const bf16x8*)&Bs[nb][swz(wn * 32 + ni * 16 + lr, (kk) * 32 + lk)]; \
        barrier_nodrain();                                                    \
        __builtin_amdgcn_s_setprio(1);                                        \
        _Pragma("unroll")                                                     \
        for (int mi = 0; mi < 4; mi++)                                        \
            _Pragma("unroll")                                                 \
            for (int ni = 0; ni < 2; ni++)                                    \
                acc[mi][ni] = __builtin_amdgcn_mfma_f32_16x16x32_bf16(af[mi], bv[ni], acc[mi][ni], 0, 0, 0); \
        __builtin_amdgcn_s_setprio(0);                                        \
    }

    GD_QSZ(0);
    GD_DMA(0, 0);
    GD_WB(0);
    GD_QSZ(64);
    BARRIER_VM(6);

    for (int t = 0; t < NT; ++t) {
        const int cur = t & 1;
        if (t + 1 < NT) GD_DMA(t + 1, cur ^ 1);
        GD_MFMA_K(cur, 0);
        GD_MFMA_K(cur, 1);
        if (t + 1 < NT) {
            GD_WB(cur ^ 1);
            if (t + 2 < NT) {
                GD_QSZ((t + 2) * 64);
                BARRIER_VM(6);
            } else {
                BARRIER_VM(0);
            }
        }
    }
#undef GD_DMA
#undef GD_QSZ
#undef GD_WB
#undef GD_MFMA_K

    float* po = partials + (size_t)bz * T_DIM * H_DIM;
    const int orow = (lane >> 4) * 4;
#pragma unroll
    for (int mi = 0; mi < 4; mi++)
#pragma unroll
        for (int ni = 0; ni < 2; ni++) {
#pragma unroll
            for (int r = 0; r < 4; r++) {
                int m = m0 + wm * 64 + mi * 16 + orow + r;
                int c = n0 + wn * 32 + ni * 16 + lr;
                po[(size_t)m * H_DIM + c] = acc[mi][ni][r];
            }
        }
}

// ---------------------------------------------------------------------------
template<int S>
__global__ void reduce_kernel(const float* __restrict__ partials, float* __restrict__ out) {
    size_t i = ((size_t)blockIdx.x * 256 + threadIdx.x) * 4;
    f32x4 a = *(const f32x4*)(partials + i);
#pragma unroll
    for (int s = 1; s < S; s++)
        a += *(const f32x4*)(partials + (size_t)s * T_DIM * H_DIM + i);
    *(f32x4*)(out + i) = a;
}

// ---------------------------------------------------------------------------
extern "C" void kernel_launch(void* const* d_in, const int* in_sizes, int n_in,
                              void* d_out, int out_size, void* d_ws, size_t ws_size,
                              hipStream_t stream) {
    const float* x   = (const float*)d_in[0];
    const int*   w1q = (const int*)d_in[1];
    const float* w1s = (const float*)d_in[2];
    const float* w1z = (const float*)d_in[3];
    const int*   w2q = (const int*)d_in[4];
    const float* w2s = (const float*)d_in[5];
    const float* w2z = (const float*)d_in[6];
    const int*   w3q = (const int*)d_in[7];
    const float* w3s = (const float*)d_in[8];
    const float* w3z = (const float*)d_in[9];

    bf16*  xb    = (bf16*)d_ws;                         // tiled [4][64][8192]
    bf16*  inter = xb + (size_t)T_DIM * H_DIM;          // tiled [4][224][8192]
    float* parts = (float*)(inter + (size_t)T_DIM * F_DIM);

    const size_t base   = (size_t)T_DIM * H_DIM * 2 + (size_t)T_DIM * F_DIM * 2;
    const size_t pbytes = (size_t)T_DIM * H_DIM * 4;

    cvt_x_kernel<<<dim3(2048), dim3(256), 0, stream>>>(x, xb);

    // gateup: 4 panels x 112 n-blocks = 448 blocks, 512 thr, XCD-remapped
    gemm_gateup<<<dim3(448), dim3(512), 0, stream>>>(
        xb, w1q, w1s, w1z, w3q, w3s, w3z, inter);

    if (ws_size >= base + 4 * pbytes) {
        gemm_down<4><<<dim3(512), dim3(512), 0, stream>>>(inter, w2q, w2s, w2z, parts);
        reduce_kernel<4><<<dim3(2048), dim3(256), 0, stream>>>(parts, (float*)d_out);
    } else if (ws_size >= base + 2 * pbytes) {
        gemm_down<2><<<dim3(256), dim3(512), 0, stream>>>(inter, w2q, w2s, w2z, parts);
        reduce_kernel<2><<<dim3(2048), dim3(256), 0, stream>>>(parts, (float*)d_out);
    } else {
        gemm_down<1><<<dim3(128), dim3(512), 0, stream>>>(inter, w2q, w2s, w2z, parts);
        reduce_kernel<1><<<dim3(2048), dim3(256), 0, stream>>>(parts, (float*)d_out);
    }
}

// Round 18
// 363.787 us; speedup vs baseline: 1.1632x; 1.1632x over previous
//
#include <hip/hip_runtime.h>
#include <stdint.h>

typedef __bf16 bf16;
typedef __attribute__((ext_vector_type(8))) bf16 bf16x8;
typedef __attribute__((ext_vector_type(4))) bf16 bf16x4;
typedef __attribute__((ext_vector_type(4))) float f32x4;

#define T_DIM 512
#define H_DIM 4096
#define F_DIM 14336

// LDS tiles: [rows][64] bf16, XOR-swizzled: elem = r*64 + (c ^ ((r&7)<<3)).
__device__ __forceinline__ int swz(int r, int c) {
    return r * 64 + (c ^ ((r & 7) << 3));
}

__device__ __forceinline__ int xcd_remap(int d, int chunk) {
    return (d & 7) * chunk + (d >> 3);
}

// Race-safe no-vmcnt-drain barrier (validated rounds 7/9/13/14/15).
__device__ __forceinline__ void barrier_nodrain() {
    __builtin_amdgcn_sched_barrier(0);
    asm volatile("s_waitcnt lgkmcnt(0)\n\ts_barrier" ::: "memory");
    __builtin_amdgcn_sched_barrier(0);
}

// ---------------------------------------------------------------------------
__global__ void cvt_x_kernel(const float* __restrict__ x, bf16* __restrict__ xb) {
    int i = (blockIdx.x * 256 + threadIdx.x) * 4;
    float4 v = *(const float4*)(x + i);
    bf16x4 o = {(bf16)v.x, (bf16)v.y, (bf16)v.z, (bf16)v.w};
    *(bf16x4*)(xb + i) = o;
}

// ---------------------------------------------------------------------------
// Fused gate+up: inter = silu(x@W1^T) * (x@W3^T).
// r14 structure (best known): tile 128x64, wave 64x32, dbuf LDS, 1-deep
// reg staging, one nodrain barrier per K-step, 2 blocks/CU.
// + T5: setprio(1) around MFMA cluster (2 independent blocks/CU give the
//   scheduler phase diversity to arbitrate — r17's 1-block/CU null doesn't apply).
// + QST issued before ASZ (HBM stream gets issue priority over L2-hot A).
__global__ __launch_bounds__(256, 2)
void gemm_gateup(const bf16* __restrict__ A,
                 const int* __restrict__ Wq1, const float* __restrict__ Sc1,
                 const float* __restrict__ Zr1,
                 const int* __restrict__ Wq3, const float* __restrict__ Sc3,
                 const float* __restrict__ Zr3,
                 bf16* __restrict__ inter) {
    constexpr int KD = H_DIM;
    constexpr int NT = KD / 64;                     // 64 (even)
    __shared__ __align__(16) bf16 As[2][128 * 64];  // 32 KB
    __shared__ __align__(16) bf16 Bs1[2][64 * 64];  // 16 KB
    __shared__ __align__(16) bf16 Bs3[2][64 * 64];  // 16 KB

    const int l    = xcd_remap(blockIdx.x, 112);    // 896/8
    const int bx   = l & 3;                         // M panel (replicas co-XCD)
    const int by   = l >> 2;                        // N block 0..223
    const int tid  = threadIdx.x;
    const int lane = tid & 63;
    const int wid  = tid >> 6;
    const int wm   = wid >> 1, wn = wid & 1;
    const int lr   = lane & 15;
    const int lk   = (lane >> 4) * 8;
    const int m0   = bx * 128;
    const int n0   = by * 64;
    const int grp  = by;

    const int a_r = tid >> 2;
    const int a_c = (tid & 3) * 8;
    const int b_r = (tid >> 4) * 4;
    const int b_c = (tid & 15) * 4;

    f32x4 acc1[4][2], acc3[4][2];
    const f32x4 zf = {0.f, 0.f, 0.f, 0.f};
#pragma unroll
    for (int i = 0; i < 4; i++)
#pragma unroll
        for (int j = 0; j < 2; j++) { acc1[i][j] = zf; acc3[i][j] = zf; }

    bf16x8 areg[4];
    int4   q1r[4], q3r[4];
    float4 s1r, z1r, s3r, z3r;

// q first: the HBM weight stream is the long-latency term; A/sz are L2-hot.
#define STAGE(K0)                                                                 \
    {                                                                             \
        _Pragma("unroll")                                                         \
        for (int i = 0; i < 4; i++) {                                             \
            q1r[i] = *(const int4*)(Wq1 + (size_t)(n0 + b_r + i) * KD + (K0) + b_c); \
            q3r[i] = *(const int4*)(Wq3 + (size_t)(n0 + b_r + i) * KD + (K0) + b_c); \
        }                                                                         \
        _Pragma("unroll")                                                         \
        for (int p = 0; p < 2; p++)                                               \
            _Pragma("unroll")                                                     \
            for (int h = 0; h < 2; h++)                                           \
                areg[p * 2 + h] = *(const bf16x8*)(A + (size_t)(m0 + a_r + 64 * p) * KD + (K0) + a_c + 32 * h); \
        s1r = *(const float4*)(Sc1 + (size_t)grp * KD + (K0) + b_c);              \
        z1r = *(const float4*)(Zr1 + (size_t)grp * KD + (K0) + b_c);              \
        s3r = *(const float4*)(Sc3 + (size_t)grp * KD + (K0) + b_c);              \
        z3r = *(const float4*)(Zr3 + (size_t)grp * KD + (K0) + b_c);              \
    }

#define WLDS(nb)                                                                  \
    {                                                                             \
        _Pragma("unroll")                                                         \
        for (int p = 0; p < 2; p++)                                               \
            _Pragma("unroll")                                                     \
            for (int h = 0; h < 2; h++)                                           \
                *(bf16x8*)&As[nb][swz(a_r + 64 * p, a_c + 32 * h)] = areg[p * 2 + h]; \
        float4 n1, n3;                                                            \
        n1.x = -z1r.x * s1r.x; n1.y = -z1r.y * s1r.y;                             \
        n1.z = -z1r.z * s1r.z; n1.w = -z1r.w * s1r.w;                             \
        n3.x = -z3r.x * s3r.x; n3.y = -z3r.y * s3r.y;                             \
        n3.z = -z3r.z * s3r.z; n3.w = -z3r.w * s3r.w;                             \
        _Pragma("unroll")                                                         \
        for (int i = 0; i < 4; i++) {                                             \
            bf16x4 v;                                                             \
            v[0] = (bf16)fmaf((float)q1r[i].x, s1r.x, n1.x);                      \
            v[1] = (bf16)fmaf((float)q1r[i].y, s1r.y, n1.y);                      \
            v[2] = (bf16)fmaf((float)q1r[i].z, s1r.z, n1.z);                      \
            v[3] = (bf16)fmaf((float)q1r[i].w, s1r.w, n1.w);                      \
            *(bf16x4*)&Bs1[nb][swz(b_r + i, b_c)] = v;                            \
            bf16x4 u;                                                             \
            u[0] = (bf16)fmaf((float)q3r[i].x, s3r.x, n3.x);                      \
            u[1] = (bf16)fmaf((float)q3r[i].y, s3r.y, n3.y);                      \
            u[2] = (bf16)fmaf((float)q3r[i].z, s3r.z, n3.z);                      \
            u[3] = (bf16)fmaf((float)q3r[i].w, s3r.w, n3.w);                      \
            *(bf16x4*)&Bs3[nb][swz(b_r + i, b_c)] = u;                            \
        }                                                                         \
    }

    // Prologue: tile0 -> LDS[0]; tile1 loads in flight across the barrier.
    STAGE(0);
    WLDS(0);
    STAGE(64);
    barrier_nodrain();

    for (int t = 0; t < NT; ++t) {
        const int cur = t & 1;
        // MFMA phase: 32 MFMA on LDS[cur]; next tile's loads still in flight.
#pragma unroll
        for (int kk = 0; kk < 2; kk++) {
            bf16x8 af[4], b1[2], b3[2];
#pragma unroll
            for (int mi = 0; mi < 4; mi++)
                af[mi] = *(const bf16x8*)&As[cur][swz(wm * 64 + mi * 16 + lr, kk * 32 + lk)];
#pragma unroll
            for (int ni = 0; ni < 2; ni++) {
                b1[ni] = *(const bf16x8*)&Bs1[cur][swz(wn * 32 + ni * 16 + lr, kk * 32 + lk)];
                b3[ni] = *(const bf16x8*)&Bs3[cur][swz(wn * 32 + ni * 16 + lr, kk * 32 + lk)];
            }
            __builtin_amdgcn_s_setprio(1);
#pragma unroll
            for (int mi = 0; mi < 4; mi++)
#pragma unroll
                for (int ni = 0; ni < 2; ni++) {
                    acc1[mi][ni] = __builtin_amdgcn_mfma_f32_16x16x32_bf16(af[mi], b1[ni], acc1[mi][ni], 0, 0, 0);
                    acc3[mi][ni] = __builtin_amdgcn_mfma_f32_16x16x32_bf16(af[mi], b3[ni], acc3[mi][ni], 0, 0, 0);
                }
            __builtin_amdgcn_s_setprio(0);
        }
        // Stage phase: write tile t+1 (regs staged step t-1), issue t+2.
        if (t + 1 < NT) {
            WLDS(cur ^ 1);
            if (t + 2 < NT) STAGE((t + 2) * 64);
            barrier_nodrain();        // lgkmcnt(0) only — loads cross freely
        }
    }
#undef STAGE
#undef WLDS

    // Epilogue: silu(gate)*up -> inter (row-major).
    const int orow = (lane >> 4) * 4;
#pragma unroll
    for (int mi = 0; mi < 4; mi++)
#pragma unroll
        for (int ni = 0; ni < 2; ni++) {
#pragma unroll
            for (int r = 0; r < 4; r++) {
                int m = m0 + wm * 64 + mi * 16 + orow + r;
                int c = n0 + wn * 32 + ni * 16 + lr;
                float g = acc1[mi][ni][r];
                float u = acc3[mi][ni][r];
                float s = g / (1.0f + __expf(-g));
                inter[(size_t)m * F_DIM + c] = (bf16)(s * u);
            }
        }
}

// ---------------------------------------------------------------------------
// Down proj, split-K: tile 128x64, wave 64x32, same pipeline + setprio.
template<int SPLITK>
__global__ __launch_bounds__(256, 3)
void gemm_down(const bf16* __restrict__ A, const int* __restrict__ Wq,
               const float* __restrict__ Sc, const float* __restrict__ Zr,
               float* __restrict__ partials) {
    constexpr int KD = F_DIM;
    constexpr int KC = KD / SPLITK;
    constexpr int NT = KC / 64;                     // 56 (even)
    __shared__ __align__(16) bf16 As[2][128 * 64];  // 32 KB
    __shared__ __align__(16) bf16 Bs[2][64 * 64];   // 16 KB

    const int l    = xcd_remap(blockIdx.x, 32 * SPLITK);
    const int bx   = l & 3;
    const int by   = (l >> 2) & 63;
    const int bz   = l >> 8;
    const int tid  = threadIdx.x;
    const int lane = tid & 63;
    const int wid  = tid >> 6;
    const int wm   = wid >> 1, wn = wid & 1;
    const int lr   = lane & 15;
    const int lk   = (lane >> 4) * 8;
    const int m0   = bx * 128;
    const int n0   = by * 64;
    const int grp  = by;
    const int kbeg = bz * KC;

    const int a_r = tid >> 2;
    const int a_c = (tid & 3) * 8;
    const int b_r = (tid >> 4) * 4;
    const int b_c = (tid & 15) * 4;

    f32x4 acc[4][2];
    const f32x4 zf = {0.f, 0.f, 0.f, 0.f};
#pragma unroll
    for (int i = 0; i < 4; i++)
#pragma unroll
        for (int j = 0; j < 2; j++) acc[i][j] = zf;

    bf16x8 areg[4];
    int4   qr[4];
    float4 sr, zr;

#define STAGE(K0)                                                                 \
    {                                                                             \
        _Pragma("unroll")                                                         \
        for (int i = 0; i < 4; i++)                                               \
            qr[i] = *(const int4*)(Wq + (size_t)(n0 + b_r + i) * KD + kbeg + (K0) + b_c); \
        _Pragma("unroll")                                                         \
        for (int p = 0; p < 2; p++)                                               \
            _Pragma("unroll")                                                     \
            for (int h = 0; h < 2; h++)                                           \
                areg[p * 2 + h] = *(const bf16x8*)(A + (size_t)(m0 + a_r + 64 * p) * KD + kbeg + (K0) + a_c + 32 * h); \
        sr = *(const float4*)(Sc + (size_t)grp * KD + kbeg + (K0) + b_c);         \
        zr = *(const float4*)(Zr + (size_t)grp * KD + kbeg + (K0) + b_c);         \
    }

#define WLDS(nb)                                                                  \
    {                                                                             \
        _Pragma("unroll")                                                         \
        for (int p = 0; p < 2; p++)                                               \
            _Pragma("unroll")                                                     \
            for (int h = 0; h < 2; h++)                                           \
                *(bf16x8*)&As[nb][swz(a_r + 64 * p, a_c + 32 * h)] = areg[p * 2 + h]; \
        float4 nz;                                                                \
        nz.x = -zr.x * sr.x; nz.y = -zr.y * sr.y;                                 \
        nz.z = -zr.z * sr.z; nz.w = -zr.w * sr.w;                                 \
        _Pragma("unroll")                                                         \
        for (int i = 0; i < 4; i++) {                                             \
            bf16x4 v;                                                             \
            v[0] = (bf16)fmaf((float)qr[i].x, sr.x, nz.x);                        \
            v[1] = (bf16)fmaf((float)qr[i].y, sr.y, nz.y);                        \
            v[2] = (bf16)fmaf((float)qr[i].z, sr.z, nz.z);                        \
            v[3] = (bf16)fmaf((float)qr[i].w, sr.w, nz.w);                        \
            *(bf16x4*)&Bs[nb][swz(b_r + i, b_c)] = v;                             \
        }                                                                         \
    }

    STAGE(0);
    WLDS(0);
    STAGE(64);
    barrier_nodrain();

    for (int t = 0; t < NT; ++t) {
        const int cur = t & 1;
#pragma unroll
        for (int kk = 0; kk < 2; kk++) {
            bf16x8 af[4], bfr[2];
#pragma unroll
            for (int mi = 0; mi < 4; mi++)
                af[mi] = *(const bf16x8*)&As[cur][swz(wm * 64 + mi * 16 + lr, kk * 32 + lk)];
#pragma unroll
            for (int ni = 0; ni < 2; ni++)
                bfr[ni] = *(const bf16x8*)&Bs[cur][swz(wn * 32 + ni * 16 + lr, kk * 32 + lk)];
            __builtin_amdgcn_s_setprio(1);
#pragma unroll
            for (int mi = 0; mi < 4; mi++)
#pragma unroll
                for (int ni = 0; ni < 2; ni++)
                    acc[mi][ni] = __builtin_amdgcn_mfma_f32_16x16x32_bf16(af[mi], bfr[ni], acc[mi][ni], 0, 0, 0);
            __builtin_amdgcn_s_setprio(0);
        }
        if (t + 1 < NT) {
            WLDS(cur ^ 1);
            if (t + 2 < NT) STAGE((t + 2) * 64);
            barrier_nodrain();
        }
    }
#undef STAGE
#undef WLDS

    float* po = partials + (size_t)bz * T_DIM * H_DIM;
    const int orow = (lane >> 4) * 4;
#pragma unroll
    for (int mi = 0; mi < 4; mi++)
#pragma unroll
        for (int ni = 0; ni < 2; ni++) {
#pragma unroll
            for (int r = 0; r < 4; r++) {
                int m = m0 + wm * 64 + mi * 16 + orow + r;
                int c = n0 + wn * 32 + ni * 16 + lr;
                po[(size_t)m * H_DIM + c] = acc[mi][ni][r];
            }
        }
}

// ---------------------------------------------------------------------------
template<int S>
__global__ void reduce_kernel(const float* __restrict__ partials, float* __restrict__ out) {
    size_t i = ((size_t)blockIdx.x * 256 + threadIdx.x) * 4;
    f32x4 a = *(const f32x4*)(partials + i);
#pragma unroll
    for (int s = 1; s < S; s++)
        a += *(const f32x4*)(partials + (size_t)s * T_DIM * H_DIM + i);
    *(f32x4*)(out + i) = a;
}

// ---------------------------------------------------------------------------
extern "C" void kernel_launch(void* const* d_in, const int* in_sizes, int n_in,
                              void* d_out, int out_size, void* d_ws, size_t ws_size,
                              hipStream_t stream) {
    const float* x   = (const float*)d_in[0];
    const int*   w1q = (const int*)d_in[1];
    const float* w1s = (const float*)d_in[2];
    const float* w1z = (const float*)d_in[3];
    const int*   w2q = (const int*)d_in[4];
    const float* w2s = (const float*)d_in[5];
    const float* w2z = (const float*)d_in[6];
    const int*   w3q = (const int*)d_in[7];
    const float* w3s = (const float*)d_in[8];
    const float* w3z = (const float*)d_in[9];

    bf16*  xb    = (bf16*)d_ws;                         // [512][4096]  bf16
    bf16*  inter = xb + (size_t)T_DIM * H_DIM;          // [512][14336] bf16
    float* parts = (float*)(inter + (size_t)T_DIM * F_DIM);

    const size_t base   = (size_t)T_DIM * H_DIM * 2 + (size_t)T_DIM * F_DIM * 2;
    const size_t pbytes = (size_t)T_DIM * H_DIM * 4;

    cvt_x_kernel<<<dim3(2048), dim3(256), 0, stream>>>(x, xb);

    // gateup: (M/128=4) x (F/64=224) = 896 blocks, 1-D XCD-remapped
    gemm_gateup<<<dim3(896), dim3(256), 0, stream>>>(
        xb, w1q, w1s, w1z, w3q, w3s, w3z, inter);

    if (ws_size >= base + 4 * pbytes) {
        gemm_down<4><<<dim3(1024), dim3(256), 0, stream>>>(inter, w2q, w2s, w2z, parts);
        reduce_kernel<4><<<dim3(2048), dim3(256), 0, stream>>>(parts, (float*)d_out);
    } else if (ws_size >= base + 2 * pbytes) {
        gemm_down<2><<<dim3(512), dim3(256), 0, stream>>>(inter, w2q, w2s, w2z, parts);
        reduce_kernel<2><<<dim3(2048), dim3(256), 0, stream>>>(parts, (float*)d_out);
    } else {
        gemm_down<1><<<dim3(256), dim3(256), 0, stream>>>(inter, w2q, w2s, w2z, parts);
        reduce_kernel<1><<<dim3(2048), dim3(256), 0, stream>>>(parts, (float*)d_out);
    }
}